// Round 12
// baseline (61.476 us; speedup 1.0000x reference)
//
#include <hip/hip_runtime.h>

#define NB_IMG   2048
#define GSQ      169                  // 13*13
#define NCELLS   (NB_IMG * GSQ)       // 346112
#define NANCH    5
#define ANCH_FLOATS  (25 * GSQ)       // 4225
#define BATCH_FLOATS (125 * GSQ)      // 21125
#define CLS_FLOATS   (20 * GSQ)       // 3380 class floats per (b,anchor)
#define REC_SLOTS 16
#define PART_BYTES ((size_t)NB_IMG * REC_SLOTS * sizeof(double))  // 262144
#define LIST_CAP  4744                // >= 5*846 + 511 pad (absolute worst case)

// Record slots: [0] coord sq  [1] conf sq obj  [2] conf sq noobj
// [3..7] per-anchor class sq  [8..12] per-anchor obj count

template<bool ATOMIC>
__global__ __launch_bounds__(256) void detloss_main(
    const float* __restrict__ det,
    const float* __restrict__ gt,
    const float* __restrict__ aw,
    const float* __restrict__ ah,
    double* __restrict__ ws)
{
    __shared__ unsigned long long mbits[NANCH][3];  // obj ballot bits, cells 0..168
    __shared__ unsigned list[LIST_CAP];             // (a<<14)|(mask4<<10)|group_i
    __shared__ int wtot[4];
    __shared__ float red[4][8];

    const int b    = blockIdx.x;
    const int tid  = threadIdx.x;
    const int wave = tid >> 6;
    const int lane = tid & 63;
    const size_t bbase = (size_t)b * BATCH_FLOATS;

    float Scoord = 0.f, S4 = 0.f, S5 = 0.f;

    // ---------- Phase A: minimal unmasked traffic (identical to round 7/11) ----------
    if (tid < GSQ) {
        const float* dbase = det + bbase + tid;
        const float* gbase = gt  + bbase + tid;

        const float px = dbase[0 * GSQ];
        const float py = dbase[1 * GSQ];
        const float dw = dbase[2 * GSQ];
        const float dh = dbase[3 * GSQ];
        const float gx = gbase[0 * GSQ];
        const float gy = gbase[1 * GSQ];
        const float gw = gbase[2 * GSQ];
        const float gh = gbase[3 * GSQ];
        const float a2 = (gw - gx + 1.0f) * (gh - gy + 1.0f);

        #pragma unroll
        for (int k = 0; k < NANCH; ++k) {
            const float* dk = dbase + k * ANCH_FLOATS;
            const float* gk = gbase + k * ANCH_FLOATS;

            const float g4v = gk[4 * GSQ];
            const float d4v = dk[4 * GSQ];
            const bool  obj = (g4v == 1.0f);

            const float pw = dw * aw[k];
            const float ph = dh * ah[k];
            const float x1 = fmaxf(px, gx);
            const float y1 = fmaxf(py, gy);
            const float x2 = fminf(pw, gw);
            const float y2 = fminf(ph, gh);
            const float inter = (x2 - x1 + 1.0f) * (y2 - y1 + 1.0f);
            const float a1    = (pw - px + 1.0f) * (ph - py + 1.0f);
            const float iou   = inter / (a1 + a2 - inter);

            const float conf = d4v * (iou >= 0.0f ? iou : 0.0f);  // NaN -> 0 like jnp.where
            const float d4   = conf - g4v;
            const float d4sq = d4 * d4;

            S4 += obj ? d4sq : 0.0f;    // selects: avoid inf*0 -> NaN
            S5 += obj ? 0.0f : d4sq;

            if (k == 0) {
                if (obj) {              // coord from registers, no extra loads
                    float dd;
                    dd = px - gx; Scoord += dd * dd;
                    dd = py - gy; Scoord += dd * dd;
                    dd = dw - gw; Scoord += dd * dd;
                    dd = dh - gh; Scoord += dd * dd;
                }
            } else {
                if (obj) {              // gated loads: ~5% of cells fetch 8 floats
                    float dd;
                    dd = dk[0 * GSQ] - gk[0 * GSQ]; Scoord += dd * dd;
                    dd = dk[1 * GSQ] - gk[1 * GSQ]; Scoord += dd * dd;
                    dd = dk[2 * GSQ] - gk[2 * GSQ]; Scoord += dd * dd;
                    dd = dk[3 * GSQ] - gk[3 * GSQ]; Scoord += dd * dd;
                }
            }

            const unsigned long long bb = __ballot(obj);   // cell = wave*64 + lane
            if (lane == 0) mbits[k][wave] = bb;            // wave in {0,1,2}
        }
    }
    __syncthreads();   // ballots visible

    // ---------- Pass 1: all 20 group-masks per thread (funnel, unrolled) ----------
    unsigned pmask[NANCH];
    int cnt = 0;
    #pragma unroll
    for (int a = 0; a < NANCH; ++a) {
        const unsigned long long w0  = mbits[a][0];
        const unsigned long long w1  = mbits[a][1];
        const unsigned long long w2e = mbits[a][2] | (w0 << 41); // wrap cells 169..191
        const int off = (b + a + 1) & 3;      // (bbase + a*4225 + 845) & 3
        const int n4  = off ? 846 : 845;

        int r0   = 4 * tid - off;
        int cell = r0 % GSQ; if (cell < 0) cell += GSQ;
        unsigned pm = 0;
        #pragma unroll
        for (int t = 0; t < 4; ++t) {
            const int i = tid + 256 * t;
            unsigned mask4 = 0;
            if (i < n4) {
                const int wsel = cell >> 6;
                const int sh   = cell & 63;
                const unsigned long long lo = (wsel == 0) ? w0 : ((wsel == 1) ? w1 : w2e);
                const unsigned long long hi = (wsel == 0) ? w1 : w2e;
                const unsigned nib =
                    (unsigned)((lo >> sh) | ((hi << 1) << (63 - sh))) & 0xFu;
                unsigned bnd;
                if ((unsigned)r0 <= 3376u) {
                    bnd = 0xFu;
                } else {
                    bnd  = ((unsigned)(r0 + 0) < (unsigned)CLS_FLOATS ? 1u : 0u);
                    bnd |= ((unsigned)(r0 + 1) < (unsigned)CLS_FLOATS ? 2u : 0u);
                    bnd |= ((unsigned)(r0 + 2) < (unsigned)CLS_FLOATS ? 4u : 0u);
                    bnd |= ((unsigned)(r0 + 3) < (unsigned)CLS_FLOATS ? 8u : 0u);
                }
                mask4 = nib & bnd;
            }
            pm  |= mask4 << (4 * t);
            cnt += (mask4 != 0u) ? 1 : 0;
            r0  += 1024;
            cell += 10; if (cell >= GSQ) cell -= GSQ;
        }
        pmask[a] = pm;
    }

    // ---------- deterministic block-wide exclusive scan of cnt ----------
    int scan = cnt;
    #pragma unroll
    for (int d = 1; d < 64; d <<= 1) {
        const int v = __shfl_up(scan, d, 64);
        scan += (lane >= d) ? v : 0;
    }
    if (lane == 63) wtot[wave] = scan;
    __syncthreads();
    int wbase = 0;
    #pragma unroll
    for (int wv = 0; wv < 4; ++wv) wbase += (wv < wave) ? wtot[wv] : 0;
    const int total = wtot[0] + wtot[1] + wtot[2] + wtot[3];
    int pos = wbase + scan - cnt;          // exclusive prefix, fixed by (tid)

    // ---------- write entries in fixed (tid, a, t) order ----------
    #pragma unroll
    for (int a = 0; a < NANCH; ++a) {
        #pragma unroll
        for (int t = 0; t < 4; ++t) {
            const unsigned m4 = (pmask[a] >> (4 * t)) & 0xFu;
            if (m4) {
                list[pos] = ((unsigned)a << 14) | (m4 << 10) | (unsigned)(tid + 256 * t);
                ++pos;
            }
        }
    }
    const int totalPad = (total + 511) & ~511;   // multiple of 512 -> guard-free bodies
    for (int p = total + tid; p < totalPad; p += 256) list[p] = 0u;  // dummy: a=0,m=0,i=0
    __syncthreads();   // list visible

    // ---------- Pass 2: dense, guard-free, all-lane loads ----------
    const float4* dt4 = (const float4*)det;
    const float4* gt4 = (const float4*)gt;
    const unsigned bb32 = (unsigned)(b * BATCH_FLOATS);

    float Sc0 = 0.f, Sc1 = 0.f, Sc2 = 0.f, Sc3 = 0.f, Sc4 = 0.f;

    #pragma unroll 1
    for (int w = tid; w < totalPad; w += 512) {
        const unsigned eA = list[w];
        const unsigned eB = list[w + 256];       // in-bounds: totalPad % 512 == 0

        const unsigned iA = eA & 1023u, mA = (eA >> 10) & 0xFu, aA = eA >> 14;
        const unsigned iB = eB & 1023u, mB = (eB >> 10) & 0xFu, aB = eB >> 14;
        const size_t b4A = (size_t)((bb32 + aA * (unsigned)ANCH_FLOATS + 5u * GSQ) >> 2) + iA;
        const size_t b4B = (size_t)((bb32 + aB * (unsigned)ANCH_FLOATS + 5u * GSQ) >> 2) + iB;

        const float4 dvA = dt4[b4A];
        const float4 gvA = gt4[b4A];
        const float4 dvB = dt4[b4B];
        const float4 gvB = gt4[b4B];

        {
            const float d0 = dvA.x - gvA.x, d1 = dvA.y - gvA.y,
                        d2 = dvA.z - gvA.z, d3 = dvA.w - gvA.w;
            const float v0 = (mA & 1u) ? d0 * d0 : 0.f;
            const float v1 = (mA & 2u) ? d1 * d1 : 0.f;
            const float v2 = (mA & 4u) ? d2 * d2 : 0.f;
            const float v3 = (mA & 8u) ? d3 * d3 : 0.f;
            const float sv = (v0 + v1) + (v2 + v3);
            Sc0 += (aA == 0u) ? sv : 0.f;
            Sc1 += (aA == 1u) ? sv : 0.f;
            Sc2 += (aA == 2u) ? sv : 0.f;
            Sc3 += (aA == 3u) ? sv : 0.f;
            Sc4 += (aA == 4u) ? sv : 0.f;
        }
        {
            const float d0 = dvB.x - gvB.x, d1 = dvB.y - gvB.y,
                        d2 = dvB.z - gvB.z, d3 = dvB.w - gvB.w;
            const float v0 = (mB & 1u) ? d0 * d0 : 0.f;
            const float v1 = (mB & 2u) ? d1 * d1 : 0.f;
            const float v2 = (mB & 4u) ? d2 * d2 : 0.f;
            const float v3 = (mB & 8u) ? d3 * d3 : 0.f;
            const float sv = (v0 + v1) + (v2 + v3);
            Sc0 += (aB == 0u) ? sv : 0.f;
            Sc1 += (aB == 1u) ? sv : 0.f;
            Sc2 += (aB == 2u) ? sv : 0.f;
            Sc3 += (aB == 3u) ? sv : 0.f;
            Sc4 += (aB == 4u) ? sv : 0.f;
        }
    }

    // ---------- block reduction: 8 float slots; counts via popc ----------
    float vals[8] = {Scoord, S4, S5, Sc0, Sc1, Sc2, Sc3, Sc4};
    #pragma unroll
    for (int i = 0; i < 8; ++i) {
        #pragma unroll
        for (int off2 = 32; off2 > 0; off2 >>= 1)
            vals[i] += __shfl_down(vals[i], off2, 64);
    }

    if (lane == 0) {
        #pragma unroll
        for (int i = 0; i < 8; ++i) red[wave][i] = vals[i];
    }
    __syncthreads();

    if (tid < 13) {
        double s;
        if (tid < 8) {
            s = (double)red[0][tid] + (double)red[1][tid] +
                (double)red[2][tid] + (double)red[3][tid];
        } else {
            const int k = tid - 8;                  // exact integer count from ballots
            s = (double)(__popcll(mbits[k][0]) + __popcll(mbits[k][1]) +
                         __popcll(mbits[k][2]));
        }
        if (ATOMIC) atomicAdd(&ws[tid], s);
        else        ws[(size_t)b * REC_SLOTS + tid] = s;
    }
}

__device__ __forceinline__ void write_outputs(const double* a, float* out)
{
    const double cnt = a[8] + a[9] + a[10] + a[11] + a[12];
    const double coord = (cnt > 0.0) ? a[0] / cnt : 0.0;
    const double s4    = (cnt > 0.0) ? a[1] / cnt : 0.0;
    const double obj_loss = 5.0 * coord + s4;

    const double cntno  = (double)NCELLS * (double)NANCH - cnt;
    const double no_obj = (cntno > 0.0) ? 0.5 * a[2] / cntno : 0.0;

    double confsum = 0.0;
    for (int k = 0; k < NANCH; ++k) {
        const double ck = a[8 + k];
        if (ck > 0.0) confsum += a[3 + k] / ck;
    }
    const double loss = obj_loss + no_obj + confsum;
    out[0] = (float)loss;
    out[1] = (float)obj_loss;
    out[2] = (float)no_obj;
    out[3] = (float)confsum;
}

__global__ __launch_bounds__(256) void detloss_reduce(
    const double* __restrict__ ws, float* __restrict__ out)
{
    double loc[13];
    #pragma unroll
    for (int i = 0; i < 13; ++i) loc[i] = 0.0;

    for (int rec = threadIdx.x; rec < NB_IMG; rec += 256) {
        const double* p = ws + (size_t)rec * REC_SLOTS;
        #pragma unroll
        for (int i = 0; i < 13; ++i) loc[i] += p[i];
    }

    #pragma unroll
    for (int i = 0; i < 13; ++i) {
        #pragma unroll
        for (int off = 32; off > 0; off >>= 1)
            loc[i] += __shfl_down(loc[i], off, 64);
    }

    __shared__ double red[4][13];
    const int wave = threadIdx.x >> 6;
    const int lane = threadIdx.x & 63;
    if (lane == 0) {
        #pragma unroll
        for (int i = 0; i < 13; ++i) red[wave][i] = loc[i];
    }
    __syncthreads();

    if (threadIdx.x == 0) {
        double a[13];
        #pragma unroll
        for (int i = 0; i < 13; ++i)
            a[i] = red[0][i] + red[1][i] + red[2][i] + red[3][i];
        write_outputs(a, out);
    }
}

__global__ void detloss_final(const double* __restrict__ acc, float* __restrict__ out)
{
    if (threadIdx.x == 0 && blockIdx.x == 0) {
        double a[13];
        for (int i = 0; i < 13; ++i) a[i] = acc[i];
        write_outputs(a, out);
    }
}

extern "C" void kernel_launch(void* const* d_in, const int* in_sizes, int n_in,
                              void* d_out, int out_size, void* d_ws, size_t ws_size,
                              hipStream_t stream)
{
    const float* det = (const float*)d_in[0];
    const float* gt  = (const float*)d_in[1];
    const float* aw  = (const float*)d_in[2];
    const float* ah  = (const float*)d_in[3];
    double* ws  = (double*)d_ws;
    float*  out = (float*)d_out;

    if (ws_size >= PART_BYTES) {
        detloss_main<false><<<NB_IMG, 256, 0, stream>>>(det, gt, aw, ah, ws);
        detloss_reduce<<<1, 256, 0, stream>>>(ws, out);
    } else {
        hipMemsetAsync(ws, 0, 13 * sizeof(double), stream);
        detloss_main<true><<<NB_IMG, 256, 0, stream>>>(det, gt, aw, ah, ws);
        detloss_final<<<1, 64, 0, stream>>>(ws, out);
    }
}

// Round 13
// 58.080 us; speedup vs baseline: 1.0585x; 1.0585x over previous
//
#include <hip/hip_runtime.h>

#define NB_IMG   2048
#define GSQ      169                  // 13*13
#define NCELLS   (NB_IMG * GSQ)       // 346112
#define NANCH    5
#define ANCH_FLOATS  (25 * GSQ)       // 4225
#define BATCH_FLOATS (125 * GSQ)      // 21125
#define CLS_FLOATS   (20 * GSQ)       // 3380 class floats per (b,anchor)
#define REC_SLOTS 16
#define PART_BYTES ((size_t)NB_IMG * REC_SLOTS * sizeof(double))  // 262144

// Record slots: [0] coord sq  [1] conf sq obj  [2] conf sq noobj
// [3..7] per-anchor class sq  [8..12] per-anchor obj count

template<bool ATOMIC>
__global__ __launch_bounds__(256) void detloss_main(
    const float* __restrict__ det,
    const float* __restrict__ gt,
    const float* __restrict__ aw,
    const float* __restrict__ ah,
    double* __restrict__ ws)
{
    __shared__ unsigned long long mbits[NANCH][3];  // obj ballot bits, cells 0..168
    __shared__ float red[4][8];

    const int b    = blockIdx.x;
    const int tid  = threadIdx.x;
    const int wave = tid >> 6;
    const int lane = tid & 63;
    const size_t bbase = (size_t)b * BATCH_FLOATS;

    float Scoord = 0.f, S4 = 0.f, S5 = 0.f;
    float Scls[NANCH] = {0.f, 0.f, 0.f, 0.f, 0.f};

    // ---------- Phase A: minimal unmasked traffic ----------
    if (tid < GSQ) {
        const float* dbase = det + bbase + tid;
        const float* gbase = gt  + bbase + tid;

        const float px = dbase[0 * GSQ];
        const float py = dbase[1 * GSQ];
        const float dw = dbase[2 * GSQ];
        const float dh = dbase[3 * GSQ];
        const float gx = gbase[0 * GSQ];
        const float gy = gbase[1 * GSQ];
        const float gw = gbase[2 * GSQ];
        const float gh = gbase[3 * GSQ];
        const float a2 = (gw - gx + 1.0f) * (gh - gy + 1.0f);

        #pragma unroll
        for (int k = 0; k < NANCH; ++k) {
            const float* dk = dbase + k * ANCH_FLOATS;
            const float* gk = gbase + k * ANCH_FLOATS;

            const float g4v = gk[4 * GSQ];
            const float d4v = dk[4 * GSQ];
            const bool  obj = (g4v == 1.0f);

            const float pw = dw * aw[k];
            const float ph = dh * ah[k];
            const float x1 = fmaxf(px, gx);
            const float y1 = fmaxf(py, gy);
            const float x2 = fminf(pw, gw);
            const float y2 = fminf(ph, gh);
            const float inter = (x2 - x1 + 1.0f) * (y2 - y1 + 1.0f);
            const float a1    = (pw - px + 1.0f) * (ph - py + 1.0f);
            const float iou   = inter / (a1 + a2 - inter);

            const float conf = d4v * (iou >= 0.0f ? iou : 0.0f);  // NaN -> 0 like jnp.where
            const float d4   = conf - g4v;
            const float d4sq = d4 * d4;

            S4 += obj ? d4sq : 0.0f;    // selects: avoid inf*0 -> NaN
            S5 += obj ? 0.0f : d4sq;

            if (k == 0) {
                if (obj) {              // coord from registers, no extra loads
                    float dd;
                    dd = px - gx; Scoord += dd * dd;
                    dd = py - gy; Scoord += dd * dd;
                    dd = dw - gw; Scoord += dd * dd;
                    dd = dh - gh; Scoord += dd * dd;
                }
            } else {
                if (obj) {              // gated loads: ~5% of cells fetch 8 floats
                    float dd;
                    dd = dk[0 * GSQ] - gk[0 * GSQ]; Scoord += dd * dd;
                    dd = dk[1 * GSQ] - gk[1 * GSQ]; Scoord += dd * dd;
                    dd = dk[2 * GSQ] - gk[2 * GSQ]; Scoord += dd * dd;
                    dd = dk[3 * GSQ] - gk[3 * GSQ]; Scoord += dd * dd;
                }
            }

            const unsigned long long bb = __ballot(obj);   // cell = wave*64 + lane
            if (lane == 0) mbits[k][wave] = bb;            // wave in {0,1,2}
        }
    }
    __syncthreads();   // ballots visible

    // ---------- Phase B: class channels, gated; funnel-shift nibble extraction ----------
    const float4* dt4 = (const float4*)det;
    const float4* gt4 = (const float4*)gt;

    #pragma unroll 1
    for (int a = 0; a < NANCH; ++a) {
        const unsigned long long w0  = mbits[a][0];
        const unsigned long long w1  = mbits[a][1];
        // extend word2: bits 41..63 (cells 169..191) := cells 0..22 (wrap-free extraction)
        const unsigned long long w2e = mbits[a][2] | (w0 << 41);
        if ((w0 | w1 | w2e) == 0ull) continue;     // whole slab empty (rare)

        const size_t s    = bbase + (size_t)a * ANCH_FLOATS + 5 * GSQ; // first class float
        const int    off  = (int)(s & 3);
        const size_t base4 = s >> 2;               // aligned-down float4 index
        const int    n4   = off ? 846 : 845;

        int r0    = 4 * tid - off;                 // rel offset of element 0 of my group
        int cell0 = r0 % GSQ; if (cell0 < 0) cell0 += GSQ;
        float accl = 0.f;

        #pragma unroll 1
        for (int i = tid; i < n4; i += 256, r0 += 1024) {
            // one funnel shift pulls cells c0..c0+3 (contiguous mod 169)
            const int wsel = cell0 >> 6;
            const int sh   = cell0 & 63;
            const unsigned long long lo = (wsel == 0) ? w0 : ((wsel == 1) ? w1 : w2e);
            const unsigned long long hi = (wsel == 0) ? w1 : w2e;   // unused when sh<61
            const unsigned nib =
                (unsigned)((lo >> sh) | ((hi << 1) << (63 - sh))) & 0xFu;

            unsigned bnd;
            if ((unsigned)r0 <= 3376u) {           // common case: all 4 in bounds
                bnd = 0xFu;
            } else {                               // head (r0<0) or tail groups only
                bnd  = ((unsigned)(r0 + 0) < (unsigned)CLS_FLOATS ? 1u : 0u);
                bnd |= ((unsigned)(r0 + 1) < (unsigned)CLS_FLOATS ? 2u : 0u);
                bnd |= ((unsigned)(r0 + 2) < (unsigned)CLS_FLOATS ? 4u : 0u);
                bnd |= ((unsigned)(r0 + 3) < (unsigned)CLS_FLOATS ? 8u : 0u);
            }
            const unsigned mask4 = nib & bnd;

            if (mask4) {                            // skip loads when no obj cell
                const float4 dv = dt4[base4 + i];
                const float4 gv = gt4[base4 + i];
                const float de[4] = {dv.x, dv.y, dv.z, dv.w};
                const float ge[4] = {gv.x, gv.y, gv.z, gv.w};
                #pragma unroll
                for (int e = 0; e < 4; ++e) {
                    if (mask4 & (1u << e)) {        // m == 1 exactly
                        const float dd = de[e] - ge[e];
                        accl += dd * dd;
                    }
                }
            }
            cell0 += 10;                            // 1024 mod 169 == 10
            if (cell0 >= GSQ) cell0 -= GSQ;
        }
        Scls[a] = accl;
    }

    // ---------- block reduction: 8 float slots; counts via popc ----------
    float vals[8] = {Scoord, S4, S5,
                     Scls[0], Scls[1], Scls[2], Scls[3], Scls[4]};
    #pragma unroll
    for (int i = 0; i < 8; ++i) {
        #pragma unroll
        for (int off2 = 32; off2 > 0; off2 >>= 1)
            vals[i] += __shfl_down(vals[i], off2, 64);
    }

    if (lane == 0) {
        #pragma unroll
        for (int i = 0; i < 8; ++i) red[wave][i] = vals[i];
    }
    __syncthreads();

    if (tid < 13) {
        double s;
        if (tid < 8) {
            s = (double)red[0][tid] + (double)red[1][tid] +
                (double)red[2][tid] + (double)red[3][tid];
        } else {
            const int k = tid - 8;                  // exact integer count from ballots
            s = (double)(__popcll(mbits[k][0]) + __popcll(mbits[k][1]) +
                         __popcll(mbits[k][2]));
        }
        if (ATOMIC) atomicAdd(&ws[tid], s);
        else        ws[(size_t)b * REC_SLOTS + tid] = s;
    }
}

__device__ __forceinline__ void write_outputs(const double* a, float* out)
{
    const double cnt = a[8] + a[9] + a[10] + a[11] + a[12];
    const double coord = (cnt > 0.0) ? a[0] / cnt : 0.0;
    const double s4    = (cnt > 0.0) ? a[1] / cnt : 0.0;
    const double obj_loss = 5.0 * coord + s4;

    const double cntno  = (double)NCELLS * (double)NANCH - cnt;
    const double no_obj = (cntno > 0.0) ? 0.5 * a[2] / cntno : 0.0;

    double confsum = 0.0;
    for (int k = 0; k < NANCH; ++k) {
        const double ck = a[8 + k];
        if (ck > 0.0) confsum += a[3 + k] / ck;
    }
    const double loss = obj_loss + no_obj + confsum;
    out[0] = (float)loss;
    out[1] = (float)obj_loss;
    out[2] = (float)no_obj;
    out[3] = (float)confsum;
}

__global__ __launch_bounds__(256) void detloss_reduce(
    const double* __restrict__ ws, float* __restrict__ out)
{
    double loc[13];
    #pragma unroll
    for (int i = 0; i < 13; ++i) loc[i] = 0.0;

    for (int rec = threadIdx.x; rec < NB_IMG; rec += 256) {
        const double* p = ws + (size_t)rec * REC_SLOTS;
        #pragma unroll
        for (int i = 0; i < 13; ++i) loc[i] += p[i];
    }

    #pragma unroll
    for (int i = 0; i < 13; ++i) {
        #pragma unroll
        for (int off = 32; off > 0; off >>= 1)
            loc[i] += __shfl_down(loc[i], off, 64);
    }

    __shared__ double red[4][13];
    const int wave = threadIdx.x >> 6;
    const int lane = threadIdx.x & 63;
    if (lane == 0) {
        #pragma unroll
        for (int i = 0; i < 13; ++i) red[wave][i] = loc[i];
    }
    __syncthreads();

    if (threadIdx.x == 0) {
        double a[13];
        #pragma unroll
        for (int i = 0; i < 13; ++i)
            a[i] = red[0][i] + red[1][i] + red[2][i] + red[3][i];
        write_outputs(a, out);
    }
}

__global__ void detloss_final(const double* __restrict__ acc, float* __restrict__ out)
{
    if (threadIdx.x == 0 && blockIdx.x == 0) {
        double a[13];
        for (int i = 0; i < 13; ++i) a[i] = acc[i];
        write_outputs(a, out);
    }
}

extern "C" void kernel_launch(void* const* d_in, const int* in_sizes, int n_in,
                              void* d_out, int out_size, void* d_ws, size_t ws_size,
                              hipStream_t stream)
{
    const float* det = (const float*)d_in[0];
    const float* gt  = (const float*)d_in[1];
    const float* aw  = (const float*)d_in[2];
    const float* ah  = (const float*)d_in[3];
    double* ws  = (double*)d_ws;
    float*  out = (float*)d_out;

    if (ws_size >= PART_BYTES) {
        detloss_main<false><<<NB_IMG, 256, 0, stream>>>(det, gt, aw, ah, ws);
        detloss_reduce<<<1, 256, 0, stream>>>(ws, out);
    } else {
        hipMemsetAsync(ws, 0, 13 * sizeof(double), stream);
        detloss_main<true><<<NB_IMG, 256, 0, stream>>>(det, gt, aw, ah, ws);
        detloss_final<<<1, 64, 0, stream>>>(ws, out);
    }
}